// Round 2
// baseline (119.230 us; speedup 1.0000x reference)
//
#include <hip/hip_runtime.h>

// Always (smoothed-min sliding window, W=16) over [B,T,D] fp32, two traces.
// out[b,t,d] = -log( sum_{j=0..15} exp(-5 x[b, max(t-15+j,0), d]) ) / 5
//
// R2: float4 vectorization. lane = (sq:2 | dq:4): dq = d-quad (4 consecutive
// channels -> 16B loads/stores), sq picks one of 4 sequences in the wave's
// seq-group. Each lane runs van Herk (block prefix + prev-block suffix) over
// a 32-step t-chunk with a 16-step clamped halo. All global accesses are
// float4: 4 x 256B contiguous segments per wave instruction (16 B/lane).

#define TT     8192
#define DD     64
#define BB     16
#define LCH    32            // t-steps per lane
#define CHUNKS (TT / LCH)    // 256

__device__ __forceinline__ float4 exp4n(float4 v) {
    float4 r;
    r.x = __expf(-5.0f * v.x);
    r.y = __expf(-5.0f * v.y);
    r.z = __expf(-5.0f * v.z);
    r.w = __expf(-5.0f * v.w);
    return r;
}
__device__ __forceinline__ float4 add4(float4 a, float4 b) {
    return make_float4(a.x + b.x, a.y + b.y, a.z + b.z, a.w + b.w);
}
__device__ __forceinline__ float4 mlog4(float4 v) {
    float4 r;
    r.x = -0.2f * __logf(v.x);
    r.y = -0.2f * __logf(v.y);
    r.z = -0.2f * __logf(v.z);
    r.w = -0.2f * __logf(v.w);
    return r;
}

__global__ __launch_bounds__(256) void always_minish_v2(
    const float* __restrict__ lower,
    const float* __restrict__ upper,
    float* __restrict__ out)
{
    const int lane  = threadIdx.x & 63;
    const int wv    = (blockIdx.x << 2) | (threadIdx.x >> 6);
    const int dq    = lane & 15;          // d-quad: channels 4*dq .. 4*dq+3
    const int sq    = lane >> 4;          // seq within group of 4
    const int g     = wv >> 8;            // seq group 0..7
    const int chunk = wv & (CHUNKS - 1);  // 0..255
    const int seq   = (g << 2) | sq;      // 0..31 = trace*16 + b
    const int tr    = seq >> 4;
    const int b     = seq & 15;

    const float* __restrict__ src =
        (tr ? upper : lower) + (size_t)b * TT * DD + dq * 4;
    float* __restrict__ dst = out + (size_t)seq * TT * DD + dq * 4;

    const int t0 = chunk * LCH;

    // Suffix sums (per channel) of the 16 steps before t0, clamped to t=0
    // (reproduces h0 = broadcast(x0) exactly).
    float4 s[16];
    #pragma unroll
    for (int j = 0; j < 16; ++j) {
        int t = t0 - 16 + j;
        if (t < 0) t = 0;
        s[j] = exp4n(*(const float4*)(src + (size_t)t * DD));
    }
    #pragma unroll
    for (int j = 14; j >= 0; --j) s[j] = add4(s[j], s[j + 1]);

    #pragma unroll
    for (int blk = 0; blk < LCH / 16; ++blk) {
        const int tb = t0 + blk * 16;

        float4 f[16];
        #pragma unroll
        for (int k = 0; k < 16; ++k)
            f[k] = exp4n(*(const float4*)(src + (size_t)(tb + k) * DD));

        float4 p = make_float4(0.f, 0.f, 0.f, 0.f);
        #pragma unroll
        for (int k = 0; k < 16; ++k) {
            p = add4(p, f[k]);
            const float4 w = (k < 15) ? add4(s[k + 1], p) : p;
            *(float4*)(dst + (size_t)(tb + k) * DD) = mlog4(w);
        }

        // In-place suffix of this block -> prev-block suffix for next iter.
        #pragma unroll
        for (int j = 14; j >= 0; --j) f[j] = add4(f[j], f[j + 1]);
        #pragma unroll
        for (int j = 0; j < 16; ++j) s[j] = f[j];
    }
}

extern "C" void kernel_launch(void* const* d_in, const int* in_sizes, int n_in,
                              void* d_out, int out_size, void* d_ws, size_t ws_size,
                              hipStream_t stream)
{
    const float* lower = (const float*)d_in[0];
    const float* upper = (const float*)d_in[1];
    float* out = (float*)d_out;

    // waves = 8 seq-groups * 256 chunks = 2048 -> 512 blocks of 4 waves
    dim3 grid(512), block(256);
    hipLaunchKernelGGL(always_minish_v2, grid, block, 0, stream,
                       lower, upper, out);
}